// Round 19
// baseline (58.929 us; speedup 1.0000x reference)
//
#include <hip/hip_runtime.h>
#include <hip/hip_bf16.h>

// VectorQuantizer on MI355X — single-pass bf16 MFMA screening GEMM with B
// staged to LDS via global_load_lds (pre-swizzled codebook, double-buffered,
// VERBATIM round-5 K-loop incl. its exact barrier ladder and dbuf location)
// + FUSED in-block exact resolution incl. suspect-tracker expansion
// (verbatim round-16 machinery) + NT hints on streaming traffic.
// d_out: z_q 8388608 f32, then indices 32768 as f32.

#define DEVI __device__ __forceinline__

typedef __attribute__((ext_vector_type(8))) short bf16x8;
typedef __attribute__((ext_vector_type(4))) float f32x4;

#define C_DIM   256
#define K_CODES 1024
#define S_DIM   8192
#define N_ROWS  32768
#define ZQ_ELEMS 8388608
#define TILE_M  64
#define NCHUNK  32
#define BAND1   1.0e-3f
#define REC_CAP 8192
#define UCAP    832
#define FLT_BIG 3.402823466e+38f

// ws layout
#define WS_EHI  0                 // 512KB pre-swizzled bf16 codebook (rows)
#define WS_E2F  524288
#define WS_CNT  528384
#define WS_REC  528448            // REC_CAP x 8B (int2: n, provisional k)

DEVI unsigned short f2b(float f) {                 // fp32 -> bf16 RNE
    unsigned u = __float_as_uint(f);
    u += 0x7FFFu + ((u >> 16) & 1u);
    return (unsigned short)(u >> 16);
}
DEVI unsigned umin2(unsigned a, unsigned b) { return a < b ? a : b; }
DEVI unsigned umax2(unsigned a, unsigned b) { return a > b ? a : b; }
DEVI unsigned long long ullmin2(unsigned long long a, unsigned long long b) {
    return a < b ? a : b;
}
DEVI float ntl(const float* p) { return __builtin_nontemporal_load(p); }
DEVI void nts(float* p, float v) { __builtin_nontemporal_store(v, p); }

DEVI f32x4 MF(bf16x8 a, bf16x8 b, f32x4 c) {
    return __builtin_amdgcn_mfma_f32_16x16x32_bf16(a, b, c, 0, 0, 0);
}
DEVI bf16x8 ldsfrag(const char* L, int row, int coff) {
    const int byte = row * 512 + (coff ^ ((row & 7) << 4));
    return *reinterpret_cast<const bf16x8*>(L + byte);
}
DEVI void gll16(const void* g, void* l) {          // 16B global -> LDS DMA
    __builtin_amdgcn_global_load_lds(
        (const __attribute__((address_space(1))) unsigned int*)g,
        (__attribute__((address_space(3))) unsigned int*)l, 16, 0, 0);
}

// ---- prologue: codebook -> bf16 rows, PRE-SWIZZLED 16B slots (slot ^= k&7),
//      + exact f32 norms. (r5-validated layout for gll staging.) ----
__global__ void vq_prep(const float* __restrict__ E,
                        unsigned short* __restrict__ ehi,
                        float* __restrict__ e2f, int* __restrict__ gcnt) {
    const int k = blockIdx.x;          // 1024 blocks
    const int lane = threadIdx.x;      // 64 threads, 8B granule each
    if (k == 0 && lane == 0) *gcnt = 0;
    const float4 v = reinterpret_cast<const float4*>(E + (size_t)k * C_DIM)[lane];
    double s = (double)v.x * v.x + (double)v.y * v.y
             + (double)v.z * v.z + (double)v.w * v.w;
    ushort4 h;
    h.x = f2b(v.x); h.y = f2b(v.y); h.z = f2b(v.z); h.w = f2b(v.w);
    const int phys8 = ((((lane >> 1) ^ (k & 7)) << 1) | (lane & 1));
    reinterpret_cast<ushort4*>(ehi + (size_t)k * C_DIM)[phys8] = h;
#pragma unroll
    for (int m = 32; m; m >>= 1) s += __shfl_xor(s, m, 64);
    if (lane == 0) e2f[k] = (float)s;   // fp64-exact -> f32
}

// ---------------- main fused kernel ----------------
__global__ __launch_bounds__(256, 2) void vq_main(
        const float* __restrict__ z, const float* __restrict__ E,
        const unsigned short* __restrict__ ehi,
        const float* __restrict__ e2f,
        float* __restrict__ out_zq, float* __restrict__ out_idx,
        int* __restrict__ gcnt, int2* __restrict__ grec) {
    // smraw: A-stage [64][512B] @0 (32KB) -> (after A-frag reads) B dbuf
    //        2x16KB @0 (r5 layout) -> key dump 17.4KB @0 -> z f32 [64][257]
    //        (65.8KB) -> epilogue [32][257] f32.
    __shared__ __align__(16) char smraw[65792];
    __shared__ float e2p[1024];        // 1.0f + |e_k|^2
    __shared__ int   kfinA[64];
    __shared__ int   flagA[64];
    __shared__ float znS[64];
    __shared__ unsigned long long best64[64];
    __shared__ int   units[UCAP];      // (row<<10) | code ; -1 = dead
    __shared__ int   ucnt;

    const int tid = threadIdx.x;
    const int n0 = blockIdx.x * TILE_M;
    const int b  = n0 >> 13;
    const int s0 = n0 & (S_DIM - 1);

    {   // e2p load
        const float4 v = reinterpret_cast<const float4*>(e2f)[tid];
        float4 w2; w2.x = 1.0f + v.x; w2.y = 1.0f + v.y;
        w2.z = 1.0f + v.z; w2.w = 1.0f + v.w;
        reinterpret_cast<float4*>(e2p)[tid] = w2;
    }

    // ---- stage A tile (hi only): z rows -> bf16, swizzled [64][512B] ----
    {
        const int s  = tid & 63;
        const int cg = tid >> 6;
        const float* zb = z + (size_t)b * (C_DIM * S_DIM) + s0 + s;
#pragma unroll
        for (int ci = 0; ci < 16; ++ci) {
            const int c = cg * 4 + ci * 16;
            ushort4 h;
            h.x = f2b(ntl(zb + (size_t)(c + 0) * S_DIM));
            h.y = f2b(ntl(zb + (size_t)(c + 1) * S_DIM));
            h.z = f2b(ntl(zb + (size_t)(c + 2) * S_DIM));
            h.w = f2b(ntl(zb + (size_t)(c + 3) * S_DIM));
            const int byte = s * 512 + ((c * 2) ^ ((s & 7) << 4));
            *reinterpret_cast<ushort4*>(smraw + byte) = h;
        }
    }
    __syncthreads();

    const int w    = tid >> 6;
    const int lane = tid & 63;
    const int wm   = w >> 1, wn = w & 1;
    const int q    = lane >> 4, jj = lane & 15;
    const int mycol = wn * 16 + jj;        // tracker/entry id 0..31

    bf16x8 Ah0[8], Ah1[8];
    {
        const int r0 = wm * 32 + jj, r1 = r0 + 16;
#pragma unroll
        for (int ks = 0; ks < 8; ++ks) {
            const int coff = ks * 64 + q * 16;
            Ah0[ks] = ldsfrag(smraw, r0, coff);
            Ah1[ks] = ldsfrag(smraw, r1, coff);
        }
    }
    __syncthreads();                       // A reads done -> smraw = B dbuf

    // ---- B staging via global_load_lds (r5-verbatim): dbuf at smraw+0,
    //      chunk = 16 x 1KB units; wave w stages units w*4..w*4+3. ----
#define STAGE(N, BUF)                                                         \
    { _Pragma("unroll")                                                       \
      for (int i_ = 0; i_ < 4; ++i_) {                                        \
          const int j_ = w * 4 + i_;                                          \
          gll16((const char*)ehi + ((size_t)(N) * 16 + j_) * 1024             \
                    + (size_t)lane * 16,                                      \
                smraw + (BUF) * 16384 + j_ * 1024);                           \
      } }

    STAGE(0, 0)
    __syncthreads();                       // gll(0) landed
    STAGE(1, 1)

    const int browbyte = mycol * 512;
    const int t0x = (q * 16) ^ ((jj & 7) << 4);

#define COMPUTE(N, A0, A1)                                                    \
    { const char* Lb = smraw + ((N) & 1) * 16384 + browbyte;                  \
      A0 = (f32x4){0.f, 0.f, 0.f, 0.f}; A1 = A0;                              \
      _Pragma("unroll")                                                       \
      for (int ks = 0; ks < 8; ++ks) {                                        \
          const bf16x8 bh = *reinterpret_cast<const bf16x8*>(                 \
              Lb + ((ks * 64) ^ t0x));                                        \
          A0 = MF(Ah0[ks], bh, A0); A1 = MF(Ah1[ks], bh, A1);                 \
      } }

#define UPD(A0, A1, E2V, N)                                                   \
    { _Pragma("unroll")                                                       \
      for (int r = 0; r < 4; ++r) {                                           \
          unsigned t_ = (__float_as_uint(                                     \
              __builtin_fmaf(-2.f, A0[r], E2V)) & 0xFFFFFFE0u) | (unsigned)(N);\
          unsigned lo_ = umin2(K1[r], t_), hi_ = umax2(K1[r], t_);            \
          K1[r] = lo_; K2[r] = umin2(K2[r], hi_);                             \
          t_ = (__float_as_uint(                                              \
              __builtin_fmaf(-2.f, A1[r], E2V)) & 0xFFFFFFE0u) | (unsigned)(N);\
          lo_ = umin2(K1[4 + r], t_); hi_ = umax2(K1[4 + r], t_);             \
          K1[4 + r] = lo_; K2[4 + r] = umin2(K2[4 + r], hi_);                 \
      } }

    unsigned K1[8], K2[8];
#pragma unroll
    for (int i = 0; i < 8; ++i) { K1[i] = 0xFFFFFFFFu; K2[i] = 0xFFFFFFFFu; }

    f32x4 aA0, aA1, aB0, aB1;
    float e2A, e2B;
    COMPUTE(0, aA0, aA1); e2A = e2p[mycol];

    for (int p = 0; p < 15; ++p) {
        const int n1 = 2 * p + 1;
        __syncthreads();               // buf(n1) ready; buf0 (dest) free
        STAGE(n1 + 1, 0)
        COMPUTE(n1, aB0, aB1); e2B = e2p[n1 * 32 + mycol];
        UPD(aA0, aA1, e2A, n1 - 1)     // deferred: overlaps MFMA above
        const int n2 = 2 * p + 2;
        __syncthreads();
        if (n2 + 1 < NCHUNK) STAGE(n2 + 1, 1)
        COMPUTE(n2, aA0, aA1); e2A = e2p[n2 * 32 + mycol];
        UPD(aB0, aB1, e2B, n2 - 1)
    }
    __syncthreads();
    COMPUTE(31, aB0, aB1); e2B = e2p[31 * 32 + mycol];
    UPD(aA0, aA1, e2A, 30)
    UPD(aB0, aB1, e2B, 31)

    // ---- dump per-tracker top-2 keys + prefill unit list ----
    __syncthreads();                       // all compute done; smraw reusable
    if (tid == 0) ucnt = 0;
    for (int i = tid; i < UCAP; i += 256) units[i] = -1;
#pragma unroll
    for (int t = 0; t < 2; ++t) {
#pragma unroll
        for (int r = 0; r < 4; ++r) {
            const int sl = t * 4 + r;
            const int row = wm * 32 + t * 16 + q * 4 + r;
            *reinterpret_cast<int2*>(smraw + row * 272 + mycol * 8) =
                make_int2((int)K1[sl], (int)K2[sl]);
        }
    }
    __syncthreads();

    // ---- leader: winner + candidate units (incl. suspect-tracker expand) --
    if (tid < 64) {
        const char* dmp = smraw + tid * 272;
        unsigned kmin = 0xFFFFFFFFu; int emin = 0;
#pragma unroll 4
        for (int e = 0; e < 32; ++e) {
            const unsigned k1 = (unsigned)
                reinterpret_cast<const int2*>(dmp + e * 8)->x;
            if (k1 < kmin) { kmin = k1; emin = e; }
        }
        const int kmincode = (int)((kmin & 31u) << 5) | emin;
        const float dminf = __uint_as_float(kmin & 0xFFFFFFE0u);
        const unsigned limk =
            (__float_as_uint(dminf + BAND1) & 0xFFFFFFE0u) | 31u;
        int cnt = 0, nfb = 0, fb0 = 0, fb1 = 0;
#pragma unroll 4
        for (int e = 0; e < 32; ++e) {
            const int2 v = *reinterpret_cast<const int2*>(dmp + e * 8);
            if ((unsigned)v.x <= limk) {
                const int code = (int)(((unsigned)v.x & 31u) << 5) | e;
                cnt += (code != kmincode);
            }
            if ((unsigned)v.y <= limk) {
                if (nfb == 0) fb0 = e; else if (nfb == 1) fb1 = e;
                ++nfb;
            }
        }
        kfinA[tid] = kmincode;
        flagA[tid] = 0;
        if (cnt > 0 || nfb > 0) {
            bool ov = (cnt > 16 || nfb > 2);
            if (!ov) {
                const int need = 1 + cnt + 32 * nfb;
                const int base = atomicAdd(&ucnt, need);
                if (base + need <= UCAP) {
                    flagA[tid] = 1;
                    best64[tid] = 0xFFFFFFFFFFFFFFFFull;
                    int p = base;
                    units[p++] = (tid << 10) | kmincode;
                    for (int e = 0; e < 32; ++e) {
                        const int2 v = *reinterpret_cast<const int2*>(dmp + e * 8);
                        if ((unsigned)v.x <= limk) {
                            const int code = (int)(((unsigned)v.x & 31u) << 5) | e;
                            if (code != kmincode) units[p++] = (tid << 10) | code;
                        }
                    }
                    if (nfb >= 1)
                        for (int c = 0; c < 32; ++c)
                            units[p++] = (tid << 10) | (c << 5) | fb0;
                    if (nfb >= 2)
                        for (int c = 0; c < 32; ++c)
                            units[p++] = (tid << 10) | (c << 5) | fb1;
                } else ov = true;          // capacity: punt whole row
            }
            if (ov) {
                const int slot = atomicAdd(gcnt, 1);
                if (slot < REC_CAP) grec[slot] = make_int2(n0 + tid, kmincode);
            }
        }
    }
    __syncthreads();                       // leader done; dump region dead

    // ---- restage z tile as f32 [64][257] (non-temporal re-read) ----
    {
        const int s  = tid & 63;
        const int cg = tid >> 6;
        const float* zb = z + (size_t)b * (C_DIM * S_DIM) + s0 + s;
        float* zr = reinterpret_cast<float*>(smraw) + s * 257;
#pragma unroll
        for (int ci = 0; ci < 16; ++ci) {
            const int c = cg * 4 + ci * 16;
            zr[c + 0] = ntl(zb + (size_t)(c + 0) * S_DIM);
            zr[c + 1] = ntl(zb + (size_t)(c + 1) * S_DIM);
            zr[c + 2] = ntl(zb + (size_t)(c + 2) * S_DIM);
            zr[c + 3] = ntl(zb + (size_t)(c + 3) * S_DIM);
        }
    }
    __syncthreads();

    // ---- phase A: znorm for flagged rows (fp64-exact -> f32) ----
    if (tid < 64 && flagA[tid]) {
        const float* zr = reinterpret_cast<const float*>(smraw) + tid * 257;
        double a0 = 0.0, a1 = 0.0, a2 = 0.0, a3 = 0.0;
#pragma unroll 8
        for (int c = 0; c < 256; c += 4) {
            const double v0 = zr[c], v1 = zr[c+1], v2 = zr[c+2], v3 = zr[c+3];
            a0 = fma(v0, v0, a0); a1 = fma(v1, v1, a1);
            a2 = fma(v2, v2, a2); a3 = fma(v3, v3, a3);
        }
        znS[tid] = (float)((a0 + a1) + (a2 + a3));
    }
    __syncthreads();

    // ---- phase B: unit eval (fp64 dot -> numpy-f32 d), per-row atomic min --
    {
        const int nu = (ucnt < UCAP) ? ucnt : UCAP;
        for (int u = tid; u < nu; u += 256) {
            const int enc = units[u];
            if (enc < 0) continue;         // sentinel (punted row's gap)
            const int row = enc >> 10, k = enc & 1023;
            const float* zr = reinterpret_cast<const float*>(smraw) + row * 257;
            const float* er = E + (size_t)k * C_DIM;
            double a0 = 0.0, a1 = 0.0, a2 = 0.0, a3 = 0.0;
#pragma unroll 8
            for (int c = 0; c < 256; c += 4) {
                a0 = fma((double)zr[c+0], (double)er[c+0], a0);
                a1 = fma((double)zr[c+1], (double)er[c+1], a1);
                a2 = fma((double)zr[c+2], (double)er[c+2], a2);
                a3 = fma((double)zr[c+3], (double)er[c+3], a3);
            }
            const float t32 = (float)((a0 + a1) + (a2 + a3));
            const float d = (znS[row] + e2f[k]) - 2.0f * t32;
            const unsigned long long key =
                ((unsigned long long)__float_as_uint(d) << 32) | (unsigned)k;
            atomicMin(&best64[row], key);
        }
    }
    __syncthreads();

    // ---- finalize ----
    if (tid < 64) {
        if (flagA[tid])
            kfinA[tid] = (int)(best64[tid] & 0xFFFFFFFFull);
        nts(out_idx + n0 + tid, (float)kfinA[tid]); // provisional for fall rows
    }

    // ---- epilogue: gather code rows in two 32-row halves via [32][257] f32
#pragma unroll
    for (int h = 0; h < 2; ++h) {
        __syncthreads();
        {
            const int slot = tid & 31;
            const int cg   = tid >> 5;         // 8 col groups of 32
            const int kk   = kfinA[h * 32 + slot];
            const float4* er = reinterpret_cast<const float4*>(
                E + (size_t)kk * C_DIM + cg * 32);
            float* lb = reinterpret_cast<float*>(smraw) + slot * 257 + cg * 32;
#pragma unroll
            for (int i = 0; i < 8; ++i) {
                const float4 v = er[i];
                lb[4 * i + 0] = v.x; lb[4 * i + 1] = v.y;
                lb[4 * i + 2] = v.z; lb[4 * i + 3] = v.w;
            }
        }
        __syncthreads();
        {
            const int sg = tid & 31;
            const int cg = tid >> 5;
            float* ob = out_zq + (size_t)b * (C_DIM * S_DIM) + s0 + h * 32 + sg;
            const float* lr = reinterpret_cast<const float*>(smraw) + sg * 257;
#pragma unroll
            for (int i = 0; i < 32; ++i) {
                const int c = cg * 32 + i;
                nts(ob + (size_t)c * S_DIM, lr[c]);
            }
        }
    }
}

// ---------------- fallback: full 1024-code fp64 scan (rare rows) ----------
__global__ __launch_bounds__(256) void vq_fall(
        const float* __restrict__ z, const float* __restrict__ E,
        const float* __restrict__ e2f,
        const int* __restrict__ gcnt, const int2* __restrict__ grec,
        float* __restrict__ out_zq, float* __restrict__ out_idx) {
    __shared__ float zsh[256];
    __shared__ double dpart[4];
    __shared__ unsigned long long wbest[4];

    const int tid = threadIdx.x;
    const int w = tid >> 6, lane = tid & 63;
    int count = gcnt[0]; if (count > REC_CAP) count = REC_CAP;

    for (int ri = blockIdx.x; ri < count; ri += gridDim.x) {
        const int2 rc = grec[ri];
        const int n = rc.x, kmin = rc.y;
        const int b = n >> 13, s = n & (S_DIM - 1);
        __syncthreads();                   // guard LDS reuse across rows
        const float zc = z[((size_t)(b * C_DIM + tid)) * S_DIM + s];
        zsh[tid] = zc;
        double p = (double)zc * (double)zc;
#pragma unroll
        for (int m = 32; m; m >>= 1) p += __shfl_xor(p, m, 64);
        if (lane == 0) dpart[w] = p;
        __syncthreads();
        const float znf = (float)((dpart[0] + dpart[1]) + (dpart[2] + dpart[3]));

        unsigned long long best = 0xFFFFFFFFFFFFFFFFull;
        for (int j = 0; j < 4; ++j) {      // 4 codes per thread
            const int k = j * 256 + tid;
            const float4* er = reinterpret_cast<const float4*>(
                E + (size_t)k * C_DIM);
            double a0 = 0.0, a1 = 0.0, a2 = 0.0, a3 = 0.0;   // 4-acc ILP
#pragma unroll 8
            for (int i = 0; i < 64; ++i) {
                const float4 ev = er[i];
                const float4 zl = reinterpret_cast<const float4*>(zsh)[i];
                a0 = fma((double)zl.x, (double)ev.x, a0);
                a1 = fma((double)zl.y, (double)ev.y, a1);
                a2 = fma((double)zl.z, (double)ev.z, a2);
                a3 = fma((double)zl.w, (double)ev.w, a3);
            }
            const float t32 = (float)((a0 + a1) + (a2 + a3));
            const float d = (znf + e2f[k]) - 2.0f * t32;
            best = ullmin2(best,
                ((unsigned long long)__float_as_uint(d) << 32) | (unsigned)k);
        }
#pragma unroll
        for (int m = 32; m; m >>= 1)
            best = ullmin2(best, (unsigned long long)__shfl_xor(
                (long long)best, m, 64));
        if (lane == 0) wbest[w] = best;
        __syncthreads();
        const unsigned long long fin =
            ullmin2(ullmin2(wbest[0], wbest[1]), ullmin2(wbest[2], wbest[3]));
        const int bk = (int)(fin & 0xFFFFFFFFull);
        if (tid == 0) out_idx[n] = (float)bk;
        if (bk != kmin) {                  // winner changed: rewrite z_q row
            out_zq[((size_t)(b * C_DIM + tid)) * S_DIM + s] =
                E[(size_t)bk * C_DIM + tid];
        }
    }
}

extern "C" void kernel_launch(void* const* d_in, const int* in_sizes, int n_in,
                              void* d_out, int out_size, void* d_ws, size_t ws_size,
                              hipStream_t stream) {
    (void)in_sizes; (void)n_in; (void)out_size; (void)ws_size;
    const float* z = (const float*)d_in[0];
    const float* E = (const float*)d_in[1];
    char* wsb = (char*)d_ws;
    unsigned short* ehi = (unsigned short*)(wsb + WS_EHI);   // pre-swizzled
    float* e2f = (float*)(wsb + WS_E2F);
    int*   cnt = (int*)  (wsb + WS_CNT);
    int2*  rec = (int2*) (wsb + WS_REC);
    float* out = (float*)d_out;

    vq_prep<<<dim3(K_CODES), dim3(64), 0, stream>>>(E, ehi, e2f, cnt);
    vq_main<<<dim3(N_ROWS / TILE_M), dim3(256), 0, stream>>>(
        z, E, ehi, e2f, out, out + ZQ_ELEMS, cnt, rec);
    vq_fall<<<dim3(1024), dim3(256), 0, stream>>>(
        z, E, e2f, cnt, rec, out, out + ZQ_ELEMS);
}

// Round 20
// 51.596 us; speedup vs baseline: 1.1421x; 1.1421x over previous
//
#include <hip/hip_runtime.h>
#include <hip/hip_bf16.h>

// VectorQuantizer on MI355X — FINAL (round-16 configuration, best measured:
// 51.6us total). Single-pass bf16 MFMA screening GEMM (B operand loaded
// directly into MFMA fragment registers from a pre-permuted codebook) with
// FUSED in-block exact resolution incl. suspect-tracker expansion, and
// non-temporal hints on streaming z reads / z_q+idx writes.
// d_out: z_q 8388608 f32, then indices 32768 as f32.

#define DEVI __device__ __forceinline__

typedef __attribute__((ext_vector_type(8))) short bf16x8;
typedef __attribute__((ext_vector_type(4))) float f32x4;

#define C_DIM   256
#define K_CODES 1024
#define S_DIM   8192
#define N_ROWS  32768
#define ZQ_ELEMS 8388608
#define TILE_M  64
#define NCHUNK  32
#define BAND1   1.0e-3f
#define REC_CAP 8192
#define UCAP    832
#define FLT_BIG 3.402823466e+38f

// ws layout
#define WS_EFR  0                 // 512KB fragment-permuted bf16 codebook
#define WS_E2F  524288
#define WS_CNT  528384
#define WS_REC  528448            // REC_CAP x 8B (int2: n, provisional k)

DEVI unsigned short f2b(float f) {                 // fp32 -> bf16 RNE
    unsigned u = __float_as_uint(f);
    u += 0x7FFFu + ((u >> 16) & 1u);
    return (unsigned short)(u >> 16);
}
DEVI unsigned umin2(unsigned a, unsigned b) { return a < b ? a : b; }
DEVI unsigned umax2(unsigned a, unsigned b) { return a > b ? a : b; }
DEVI unsigned long long ullmin2(unsigned long long a, unsigned long long b) {
    return a < b ? a : b;
}
DEVI float ntl(const float* p) { return __builtin_nontemporal_load(p); }
DEVI void nts(float* p, float v) { __builtin_nontemporal_store(v, p); }

DEVI f32x4 MF(bf16x8 a, bf16x8 b, f32x4 c) {
    return __builtin_amdgcn_mfma_f32_16x16x32_bf16(a, b, c, 0, 0, 0);
}
DEVI bf16x8 ldsfrag(const char* L, int row, int coff) {
    const int byte = row * 512 + (coff ^ ((row & 7) << 4));
    return *reinterpret_cast<const bf16x8*>(L + byte);
}

// ---- prologue: codebook -> MFMA-fragment-permuted bf16 + exact f32 norms ----
__global__ void vq_prep(const float* __restrict__ E,
                        unsigned short* __restrict__ efrag,
                        float* __restrict__ e2f, int* __restrict__ gcnt) {
    const int k = blockIdx.x;          // 1024 blocks
    const int lane = threadIdx.x;      // 64 threads, 8B (half-fragment) each
    if (k == 0 && lane == 0) *gcnt = 0;
    const float4 v = reinterpret_cast<const float4*>(E + (size_t)k * C_DIM)[lane];
    double s = (double)v.x * v.x + (double)v.y * v.y
             + (double)v.z * v.z + (double)v.w * v.w;
    ushort4 h;
    h.x = f2b(v.x); h.y = f2b(v.y); h.z = f2b(v.z); h.w = f2b(v.w);
    const int f = lane >> 1, half = lane & 1;
    const int ks = f >> 2, q = f & 3;
    const int jj = k & 15, wn = (k >> 4) & 1, chunk = k >> 5;
    char* dst = (char*)efrag + (size_t)chunk * 16384 + wn * 8192
              + ks * 1024 + (q * 16 + jj) * 16 + half * 8;
    *reinterpret_cast<ushort4*>(dst) = h;
#pragma unroll
    for (int m = 32; m; m >>= 1) s += __shfl_xor(s, m, 64);
    if (lane == 0) e2f[k] = (float)s;   // fp64-exact -> f32
}

// ---------------- main fused kernel ----------------
__global__ __launch_bounds__(256, 2) void vq_main(
        const float* __restrict__ z, const float* __restrict__ E,
        const unsigned short* __restrict__ efrag,
        const float* __restrict__ e2f,
        float* __restrict__ out_zq, float* __restrict__ out_idx,
        int* __restrict__ gcnt, int2* __restrict__ grec) {
    // smraw phases: A-hi stage 32KB -> key dump 17.4KB -> z f32 [64][257]
    //               (65.8KB) -> epilogue [32][257] f32 (32.9KB)
    __shared__ __align__(16) char smraw[65792];
    __shared__ float e2p[1024];        // 1.0f + |e_k|^2
    __shared__ int   kfinA[64];
    __shared__ int   flagA[64];
    __shared__ float znS[64];
    __shared__ unsigned long long best64[64];
    __shared__ int   units[UCAP];      // (row<<10) | code ; -1 = dead
    __shared__ int   ucnt;

    const int tid = threadIdx.x;
    const int n0 = blockIdx.x * TILE_M;
    const int b  = n0 >> 13;
    const int s0 = n0 & (S_DIM - 1);

    {   // e2p load
        const float4 v = reinterpret_cast<const float4*>(e2f)[tid];
        float4 w; w.x = 1.0f + v.x; w.y = 1.0f + v.y;
        w.z = 1.0f + v.z; w.w = 1.0f + v.w;
        reinterpret_cast<float4*>(e2p)[tid] = w;
    }

    // ---- stage A tile (hi only): z rows -> bf16, swizzled [64][512B] ----
    //      (non-temporal: don't let streaming z evict the codebook from L2)
    {
        const int s  = tid & 63;
        const int cg = tid >> 6;
        const float* zb = z + (size_t)b * (C_DIM * S_DIM) + s0 + s;
#pragma unroll
        for (int ci = 0; ci < 16; ++ci) {
            const int c = cg * 4 + ci * 16;
            ushort4 h;
            h.x = f2b(ntl(zb + (size_t)(c + 0) * S_DIM));
            h.y = f2b(ntl(zb + (size_t)(c + 1) * S_DIM));
            h.z = f2b(ntl(zb + (size_t)(c + 2) * S_DIM));
            h.w = f2b(ntl(zb + (size_t)(c + 3) * S_DIM));
            const int byte = s * 512 + ((c * 2) ^ ((s & 7) << 4));
            *reinterpret_cast<ushort4*>(smraw + byte) = h;
        }
    }
    __syncthreads();

    const int w    = tid >> 6;
    const int lane = tid & 63;
    const int wm   = w >> 1, wn = w & 1;
    const int q    = lane >> 4, jj = lane & 15;
    const int mycol = wn * 16 + jj;        // tracker/entry id 0..31

    bf16x8 Ah0[8], Ah1[8];
    {
        const int r0 = wm * 32 + jj, r1 = r0 + 16;
#pragma unroll
        for (int ks = 0; ks < 8; ++ks) {
            const int coff = ks * 64 + q * 16;
            Ah0[ks] = ldsfrag(smraw, r0, coff);
            Ah1[ks] = ldsfrag(smraw, r1, coff);
        }
    }
    // NOTE: no barrier needed until the key dump (smraw untouched in K-loop).

    // ---- main K-loop: B fragments straight from global into registers ----
    const char* gB = (const char*)efrag + (size_t)wn * 8192 + (size_t)lane * 16;

#define LOADB(BR, N)                                                          \
    { _Pragma("unroll")                                                       \
      for (int ks_ = 0; ks_ < 8; ++ks_)                                       \
          BR[ks_] = *reinterpret_cast<const bf16x8*>(                         \
              gB + (size_t)(N) * 16384 + ks_ * 1024); }

#define RCOMPUTE(BR, A0, A1)                                                  \
    { A0 = (f32x4){0.f, 0.f, 0.f, 0.f}; A1 = A0;                              \
      _Pragma("unroll")                                                       \
      for (int ks_ = 0; ks_ < 8; ++ks_) {                                     \
          A0 = MF(Ah0[ks_], BR[ks_], A0);                                     \
          A1 = MF(Ah1[ks_], BR[ks_], A1);                                     \
      } }

#define UPD(A0, A1, E2V, N)                                                   \
    { _Pragma("unroll")                                                       \
      for (int r = 0; r < 4; ++r) {                                           \
          unsigned t_ = (__float_as_uint(                                     \
              __builtin_fmaf(-2.f, A0[r], E2V)) & 0xFFFFFFE0u) | (unsigned)(N);\
          unsigned lo_ = umin2(K1[r], t_), hi_ = umax2(K1[r], t_);            \
          K1[r] = lo_; K2[r] = umin2(K2[r], hi_);                             \
          t_ = (__float_as_uint(                                              \
              __builtin_fmaf(-2.f, A1[r], E2V)) & 0xFFFFFFE0u) | (unsigned)(N);\
          lo_ = umin2(K1[4 + r], t_); hi_ = umax2(K1[4 + r], t_);             \
          K1[4 + r] = lo_; K2[4 + r] = umin2(K2[4 + r], hi_);                 \
      } }

    unsigned K1[8], K2[8];
#pragma unroll
    for (int i = 0; i < 8; ++i) { K1[i] = 0xFFFFFFFFu; K2[i] = 0xFFFFFFFFu; }

    bf16x8 Bc[8], Bn[8];
    LOADB(Bc, 0)
    LOADB(Bn, 1)
    f32x4 aA0, aA1, aB0, aB1;

#pragma unroll
    for (int p = 0; p < 16; ++p) {
        const int nA = 2 * p, nB = 2 * p + 1;
        RCOMPUTE(Bc, aA0, aA1)
        if (p < 15) LOADB(Bc, nA + 2)
        UPD(aA0, aA1, e2p[nA * 32 + mycol], nA)
        RCOMPUTE(Bn, aB0, aB1)
        if (p < 15) LOADB(Bn, nB + 2)
        UPD(aB0, aB1, e2p[nB * 32 + mycol], nB)
    }

    // ---- dump per-tracker top-2 keys + prefill unit list ----
    __syncthreads();                       // A-frag reads done; smraw reusable
    if (tid == 0) ucnt = 0;
    for (int i = tid; i < UCAP; i += 256) units[i] = -1;
#pragma unroll
    for (int t = 0; t < 2; ++t) {
#pragma unroll
        for (int r = 0; r < 4; ++r) {
            const int sl = t * 4 + r;
            const int row = wm * 32 + t * 16 + q * 4 + r;
            *reinterpret_cast<int2*>(smraw + row * 272 + mycol * 8) =
                make_int2((int)K1[sl], (int)K2[sl]);
        }
    }
    __syncthreads();

    // ---- leader: winner + candidate units (incl. suspect-tracker expand) --
    if (tid < 64) {
        const char* dmp = smraw + tid * 272;
        unsigned kmin = 0xFFFFFFFFu; int emin = 0;
#pragma unroll 4
        for (int e = 0; e < 32; ++e) {
            const unsigned k1 = (unsigned)
                reinterpret_cast<const int2*>(dmp + e * 8)->x;
            if (k1 < kmin) { kmin = k1; emin = e; }
        }
        const int kmincode = (int)((kmin & 31u) << 5) | emin;
        const float dminf = __uint_as_float(kmin & 0xFFFFFFE0u);
        const unsigned limk =
            (__float_as_uint(dminf + BAND1) & 0xFFFFFFE0u) | 31u;
        int cnt = 0, nfb = 0, fb0 = 0, fb1 = 0;
#pragma unroll 4
        for (int e = 0; e < 32; ++e) {
            const int2 v = *reinterpret_cast<const int2*>(dmp + e * 8);
            if ((unsigned)v.x <= limk) {
                const int code = (int)(((unsigned)v.x & 31u) << 5) | e;
                cnt += (code != kmincode);
            }
            if ((unsigned)v.y <= limk) {
                if (nfb == 0) fb0 = e; else if (nfb == 1) fb1 = e;
                ++nfb;
            }
        }
        kfinA[tid] = kmincode;
        flagA[tid] = 0;
        if (cnt > 0 || nfb > 0) {
            bool ov = (cnt > 16 || nfb > 2);
            if (!ov) {
                const int need = 1 + cnt + 32 * nfb;
                const int base = atomicAdd(&ucnt, need);
                if (base + need <= UCAP) {
                    flagA[tid] = 1;
                    best64[tid] = 0xFFFFFFFFFFFFFFFFull;
                    int p = base;
                    units[p++] = (tid << 10) | kmincode;
                    for (int e = 0; e < 32; ++e) {
                        const int2 v = *reinterpret_cast<const int2*>(dmp + e * 8);
                        if ((unsigned)v.x <= limk) {
                            const int code = (int)(((unsigned)v.x & 31u) << 5) | e;
                            if (code != kmincode) units[p++] = (tid << 10) | code;
                        }
                    }
                    if (nfb >= 1)
                        for (int c = 0; c < 32; ++c)
                            units[p++] = (tid << 10) | (c << 5) | fb0;
                    if (nfb >= 2)
                        for (int c = 0; c < 32; ++c)
                            units[p++] = (tid << 10) | (c << 5) | fb1;
                } else ov = true;          // capacity: punt whole row
            }
            if (ov) {
                const int slot = atomicAdd(gcnt, 1);
                if (slot < REC_CAP) grec[slot] = make_int2(n0 + tid, kmincode);
            }
        }
    }
    __syncthreads();                       // leader done; dump region dead

    // ---- restage z tile as f32 [64][257] (non-temporal re-read) ----
    {
        const int s  = tid & 63;
        const int cg = tid >> 6;
        const float* zb = z + (size_t)b * (C_DIM * S_DIM) + s0 + s;
        float* zr = reinterpret_cast<float*>(smraw) + s * 257;
#pragma unroll
        for (int ci = 0; ci < 16; ++ci) {
            const int c = cg * 4 + ci * 16;
            zr[c + 0] = ntl(zb + (size_t)(c + 0) * S_DIM);
            zr[c + 1] = ntl(zb + (size_t)(c + 1) * S_DIM);
            zr[c + 2] = ntl(zb + (size_t)(c + 2) * S_DIM);
            zr[c + 3] = ntl(zb + (size_t)(c + 3) * S_DIM);
        }
    }
    __syncthreads();

    // ---- phase A: znorm for flagged rows (fp64-exact -> f32) ----
    if (tid < 64 && flagA[tid]) {
        const float* zr = reinterpret_cast<const float*>(smraw) + tid * 257;
        double a0 = 0.0, a1 = 0.0, a2 = 0.0, a3 = 0.0;
#pragma unroll 8
        for (int c = 0; c < 256; c += 4) {
            const double v0 = zr[c], v1 = zr[c+1], v2 = zr[c+2], v3 = zr[c+3];
            a0 = fma(v0, v0, a0); a1 = fma(v1, v1, a1);
            a2 = fma(v2, v2, a2); a3 = fma(v3, v3, a3);
        }
        znS[tid] = (float)((a0 + a1) + (a2 + a3));
    }
    __syncthreads();

    // ---- phase B: unit eval (fp64 dot -> numpy-f32 d), per-row atomic min --
    {
        const int nu = (ucnt < UCAP) ? ucnt : UCAP;
        for (int u = tid; u < nu; u += 256) {
            const int enc = units[u];
            if (enc < 0) continue;         // sentinel (punted row's gap)
            const int row = enc >> 10, k = enc & 1023;
            const float* zr = reinterpret_cast<const float*>(smraw) + row * 257;
            const float* er = E + (size_t)k * C_DIM;
            double a0 = 0.0, a1 = 0.0, a2 = 0.0, a3 = 0.0;
#pragma unroll 8
            for (int c = 0; c < 256; c += 4) {
                a0 = fma((double)zr[c+0], (double)er[c+0], a0);
                a1 = fma((double)zr[c+1], (double)er[c+1], a1);
                a2 = fma((double)zr[c+2], (double)er[c+2], a2);
                a3 = fma((double)zr[c+3], (double)er[c+3], a3);
            }
            const float t32 = (float)((a0 + a1) + (a2 + a3));
            const float d = (znS[row] + e2f[k]) - 2.0f * t32;
            const unsigned long long key =
                ((unsigned long long)__float_as_uint(d) << 32) | (unsigned)k;
            atomicMin(&best64[row], key);
        }
    }
    __syncthreads();

    // ---- finalize ----
    if (tid < 64) {
        if (flagA[tid])
            kfinA[tid] = (int)(best64[tid] & 0xFFFFFFFFull);
        nts(out_idx + n0 + tid, (float)kfinA[tid]); // provisional for fall rows
    }

    // ---- epilogue: gather code rows in two 32-row halves via [32][257] f32
#pragma unroll
    for (int h = 0; h < 2; ++h) {
        __syncthreads();
        {
            const int slot = tid & 31;
            const int cg   = tid >> 5;         // 8 col groups of 32
            const int kk   = kfinA[h * 32 + slot];
            const float4* er = reinterpret_cast<const float4*>(
                E + (size_t)kk * C_DIM + cg * 32);
            float* lb = reinterpret_cast<float*>(smraw) + slot * 257 + cg * 32;
#pragma unroll
            for (int i = 0; i < 8; ++i) {
                const float4 v = er[i];
                lb[4 * i + 0] = v.x; lb[4 * i + 1] = v.y;
                lb[4 * i + 2] = v.z; lb[4 * i + 3] = v.w;
            }
        }
        __syncthreads();
        {
            const int sg = tid & 31;
            const int cg = tid >> 5;
            float* ob = out_zq + (size_t)b * (C_DIM * S_DIM) + s0 + h * 32 + sg;
            const float* lr = reinterpret_cast<const float*>(smraw) + sg * 257;
#pragma unroll
            for (int i = 0; i < 32; ++i) {
                const int c = cg * 32 + i;
                nts(ob + (size_t)c * S_DIM, lr[c]);
            }
        }
    }
}

// ---------------- fallback: full 1024-code fp64 scan (rare rows) ----------
__global__ __launch_bounds__(256) void vq_fall(
        const float* __restrict__ z, const float* __restrict__ E,
        const float* __restrict__ e2f,
        const int* __restrict__ gcnt, const int2* __restrict__ grec,
        float* __restrict__ out_zq, float* __restrict__ out_idx) {
    __shared__ float zsh[256];
    __shared__ double dpart[4];
    __shared__ unsigned long long wbest[4];

    const int tid = threadIdx.x;
    const int w = tid >> 6, lane = tid & 63;
    int count = gcnt[0]; if (count > REC_CAP) count = REC_CAP;

    for (int ri = blockIdx.x; ri < count; ri += gridDim.x) {
        const int2 rc = grec[ri];
        const int n = rc.x, kmin = rc.y;
        const int b = n >> 13, s = n & (S_DIM - 1);
        __syncthreads();                   // guard LDS reuse across rows
        const float zc = z[((size_t)(b * C_DIM + tid)) * S_DIM + s];
        zsh[tid] = zc;
        double p = (double)zc * (double)zc;
#pragma unroll
        for (int m = 32; m; m >>= 1) p += __shfl_xor(p, m, 64);
        if (lane == 0) dpart[w] = p;
        __syncthreads();
        const float znf = (float)((dpart[0] + dpart[1]) + (dpart[2] + dpart[3]));

        unsigned long long best = 0xFFFFFFFFFFFFFFFFull;
        for (int j = 0; j < 4; ++j) {      // 4 codes per thread
            const int k = j * 256 + tid;
            const float4* er = reinterpret_cast<const float4*>(
                E + (size_t)k * C_DIM);
            double a0 = 0.0, a1 = 0.0, a2 = 0.0, a3 = 0.0;   // 4-acc ILP
#pragma unroll 8
            for (int i = 0; i < 64; ++i) {
                const float4 ev = er[i];
                const float4 zl = reinterpret_cast<const float4*>(zsh)[i];
                a0 = fma((double)zl.x, (double)ev.x, a0);
                a1 = fma((double)zl.y, (double)ev.y, a1);
                a2 = fma((double)zl.z, (double)ev.z, a2);
                a3 = fma((double)zl.w, (double)ev.w, a3);
            }
            const float t32 = (float)((a0 + a1) + (a2 + a3));
            const float d = (znf + e2f[k]) - 2.0f * t32;
            best = ullmin2(best,
                ((unsigned long long)__float_as_uint(d) << 32) | (unsigned)k);
        }
#pragma unroll
        for (int m = 32; m; m >>= 1)
            best = ullmin2(best, (unsigned long long)__shfl_xor(
                (long long)best, m, 64));
        if (lane == 0) wbest[w] = best;
        __syncthreads();
        const unsigned long long fin =
            ullmin2(ullmin2(wbest[0], wbest[1]), ullmin2(wbest[2], wbest[3]));
        const int bk = (int)(fin & 0xFFFFFFFFull);
        if (tid == 0) out_idx[n] = (float)bk;
        if (bk != kmin) {                  // winner changed: rewrite z_q row
            out_zq[((size_t)(b * C_DIM + tid)) * S_DIM + s] =
                E[(size_t)bk * C_DIM + tid];
        }
    }
}

extern "C" void kernel_launch(void* const* d_in, const int* in_sizes, int n_in,
                              void* d_out, int out_size, void* d_ws, size_t ws_size,
                              hipStream_t stream) {
    (void)in_sizes; (void)n_in; (void)out_size; (void)ws_size;
    const float* z = (const float*)d_in[0];
    const float* E = (const float*)d_in[1];
    char* wsb = (char*)d_ws;
    unsigned short* efrag = (unsigned short*)(wsb + WS_EFR); // frag-permuted
    float* e2f = (float*)(wsb + WS_E2F);
    int*   cnt = (int*)  (wsb + WS_CNT);
    int2*  rec = (int2*) (wsb + WS_REC);
    float* out = (float*)d_out;

    vq_prep<<<dim3(K_CODES), dim3(64), 0, stream>>>(E, efrag, e2f, cnt);
    vq_main<<<dim3(N_ROWS / TILE_M), dim3(256), 0, stream>>>(
        z, E, efrag, e2f, out, out + ZQ_ELEMS, cnt, rec);
    vq_fall<<<dim3(1024), dim3(256), 0, stream>>>(
        z, E, e2f, cnt, rec, out, out + ZQ_ELEMS);
}